// Round 12
// baseline (46.542 us; speedup 1.0000x reference)
//
#include <hip/hip_runtime.h>

// NormalizingFlow: 4 layers of monotonic linear-rational splines (pyro-style),
// B=262144 rows, D=64 dims, K=8 bins.
//
// Composed 4-layer chain per dim = piecewise-Mobius, 61 interior pieces +
// 2 identity pieces (x<-3, x>=3) -> 63 pieces, det-normalized (det=1)
// ABSOLUTE fp32 coeffs. Main kernel: 4 dims per lane (dwordx4 X/OUT),
// binary coarse (3cmp) + binary fine (3cmp) search, one b128 coeff gather,
// Mobius; lad = -2 ln|den|; 16-lane DPP reduce (4 rows per unit).
// Tables stored with permuted dim column pd = (d>>2)|((d&3)<<4) so lane m,
// element j reads column m+16j (conflict-free b128 stride, folded addrs).

#define BATCH 262144
#define DIM   64
#define NLAY  4
#define NK    8

// float offsets in d_ws
#define OFF_KN0 0       // [8][64][4] boundary slots B[8c+0..3] (perm cols)
#define OFF_KN1 2048    // [8][64][4] boundary slots B[8c+4..7]
#define OFF_CRS 4096    // [7][64] coarse = B[8k+7], natural dim index
#define OFF_CF  4544    // [64][64][4] piece coeffs (A,B,C,D), perm cols

// Fused precompute: one block per dim d (64 blocks x 64 threads).
__global__ void nf_pre(const float* __restrict__ uw, const float* __restrict__ uh,
                       const float* __restrict__ ud, const float* __restrict__ ul,
                       float* __restrict__ F) {
  __shared__ double Lb[NLAY][17], Ly[NLAY][17], LM[NLAY][16][4], Ld[NLAY][16];
  __shared__ double sx[64], Fb[65];
  int d = blockIdx.x;
  int t = threadIdx.x;

  if (t < 32) {
    int l = t >> 3, k = t & 7;
    const float* pw  = uw + (l*DIM + d)*NK;
    const float* ph  = uh + (l*DIM + d)*NK;
    const float* pdv = ud + (l*DIM + d)*(NK-1);
    const float* pl  = ul + (l*DIM + d)*NK;

    float ev[NK];
    float mw = pw[0];
    for (int j = 1; j < NK; ++j) mw = fmaxf(mw, pw[j]);
    float sw = 0.f;
    for (int j = 0; j < NK; ++j) { ev[j] = expf(pw[j] - mw); sw += ev[j]; }
    float invw = 1.f / sw;
    float cwe = 0.f, cwi = 0.f;
    for (int j = 0; j <= k; ++j) {
      float vj = 1e-3f + (1.f - 1e-3f * (float)NK) * (ev[j] * invw);
      cwe = cwi; cwi += vj;
    }
    float kwL = (k == 0) ? -3.f : 6.f * cwe - 3.f;
    float kwR = (k == 7) ?  3.f : 6.f * cwi - 3.f;
    float wwk = kwR - kwL;

    float mh = ph[0];
    for (int j = 1; j < NK; ++j) mh = fmaxf(mh, ph[j]);
    float sh = 0.f;
    for (int j = 0; j < NK; ++j) { ev[j] = expf(ph[j] - mh); sh += ev[j]; }
    float invh = 1.f / sh;
    float che = 0.f, chi = 0.f;
    for (int j = 0; j <= k; ++j) {
      float vj = 1e-3f + (1.f - 1e-3f * (float)NK) * (ev[j] * invh);
      che = chi; chi += vj;
    }
    float khL = (k == 0) ? -3.f : 6.f * che - 3.f;
    float khR = (k == 7) ?  3.f : 6.f * chi - 3.f;
    float hhk = khR - khL;

    float dvk, dvk1;
    if (k == 0) dvk = 1.f;
    else { float u = pdv[k-1]; dvk  = 1e-3f + (fmaxf(u,0.f) + log1pf(expf(-fabsf(u)))); }
    if (k == 7) dvk1 = 1.f;
    else { float u = pdv[k];   dvk1 = 1e-3f + (fmaxf(u,0.f) + log1pf(expf(-fabsf(u)))); }
    float sg = 1.f / (1.f + expf(-pl[k]));
    float lmk = 0.95f * sg + 0.025f;

    float delta = hhk / wwk;
    float wbf = sqrtf(dvk / dvk1);
    float wcf = (lmk*dvk + (1.f-lmk)*wbf*dvk1) / delta;
    float yaf = khL, ybf = hhk + khL;
    float ycf = ((1.f-lmk)*yaf + lmk*wbf*ybf) / ((1.f-lmk) + lmk*wbf);

    if (k == 0) {
      Lb[l][0] = -3.0; Lb[l][16] = 3.0;
      Ly[l][0] = -3.0; Ly[l][16] = 3.0;
    }
    if (k) Lb[l][2*k] = (double)(kwL + 1.0e-6f);   // bin boundary (fp32 +EPS)
    Lb[l][2*k+1] = (double)kwL + (double)lmk*(double)wwk;  // theta==lambda
    Ly[l][2*k]   = (double)yaf;
    Ly[l][2*k+1] = (double)ycf;

    double icw = (double)kwL, iw = (double)wwk, il = (double)lmk;
    double wb = wbf, wc = wcf, ya = yaf, yb = ybf, yc = ycf;
    double n0 = ya*il, n1 = wc*yc - ya, d0 = il, d1 = wc - 1.0;
    double A = n1, Bv = n0*iw - n1*icw, C = d1, Dv = d0*iw - d1*icw;
    LM[l][2*k][0]=A; LM[l][2*k][1]=Bv; LM[l][2*k][2]=C; LM[l][2*k][3]=Dv;
    Ld[l][2*k] = log2(A*Dv - Bv*C);
    n0 = wc*yc - il*wb*yb; n1 = wb*yb - wc*yc; d0 = wc - il*wb; d1 = wb - wc;
    A = n1; Bv = n0*iw - n1*icw; C = d1; Dv = d0*iw - d1*icw;
    LM[l][2*k+1][0]=A; LM[l][2*k+1][1]=Bv; LM[l][2*k+1][2]=C; LM[l][2*k+1][3]=Dv;
    Ld[l][2*k+1] = log2(A*Dv - Bv*C);
  }
  __syncthreads();

  if (t < 60) {
    int lp  = t / 15;
    int mth = t % 15 + 1;
    double x = Lb[lp][mth];
    for (int q = lp - 1; q >= 0; --q) {
      int j = 0;
      for (int k = 1; k <= 15; ++k) j += (x >= Ly[q][k]) ? 1 : 0;
      const double* M = LM[q][j];
      x = (M[3]*x - M[1]) / (M[0] - M[2]*x);  // Mobius inverse
    }
    sx[t] = x;
  }
  __syncthreads();
  if (t < 60) {
    double x = sx[t];
    int r = 0;
    for (int s2 = 0; s2 < 60; ++s2) {
      double o = sx[s2];
      r += (o < x || (o == x && s2 < t)) ? 1 : 0;
    }
    Fb[r+1] = x;
  }
  if (t == 0)  Fb[0] = -3.0;
  if (t >= 60) Fb[t+1] = 3.0;   // Fb[61..64] geometry pads
  __syncthreads();

  int pd = ((d >> 2) | ((d & 3) << 4));   // permuted column

  // boundary slot table B[t]: B[0]=-3, B[1..60]=Fb, B[61]=3, B[62..63]=pad
  {
    int j = t;
    float bf;
    if (j == 0)       bf = -3.0f;
    else if (j <= 60) bf = (float)Fb[j];
    else if (j == 61) bf = 3.0f;
    else              bf = 1e30f;
    int cw = j >> 3, r8 = j & 7;
    if (r8 < 4) F[OFF_KN0 + (cw*DIM + pd)*4 + r8]     = bf;
    else        F[OFF_KN1 + (cw*DIM + pd)*4 + (r8-4)] = bf;
    if ((j & 7) == 7 && j <= 55) F[OFF_CRS + (j>>3)*DIM + d] = bf;  // B[8k+7]
  }

  // coeff row t: 0 and >=62 identity; 1..61 = interior piece t-1 (absolute,
  // det-normalized to 1)
  {
    float4 c4;
    if (t == 0 || t >= 62) {
      c4.x = 1.f; c4.y = 0.f; c4.z = 0.f; c4.w = 1.f;
    } else {
      int q = t - 1;
      double bl = Fb[q], br = Fb[q+1];
      float xmf = (float)(0.5*(bl+br));
      xmf = fminf(fmaxf(xmf, -3.f), 3.f);
      double y = (double)xmf;
      double A=1.0, Bv=0.0, C=0.0, Dv=1.0, ld2 = 0.0;
      for (int qq = 0; qq < NLAY; ++qq) {
        int j = 0;
        for (int k = 1; k <= 15; ++k) j += (y >= Lb[qq][k]) ? 1 : 0;
        const double* M = LM[qq][j];
        ld2 += Ld[qq][j];
        double A2 = M[0]*A + M[1]*C, B2 = M[0]*Bv + M[1]*Dv;
        double C2 = M[2]*A + M[3]*C, D2 = M[2]*Bv + M[3]*Dv;
        y = (M[0]*y + M[1]) / (M[2]*y + M[3]);
        A=A2; Bv=B2; C=C2; Dv=D2;
      }
      double sinv = exp2(-0.5 * ld2);              // det -> 1
      c4.x = (float)(A*sinv);  c4.y = (float)(Bv*sinv);
      c4.z = (float)(C*sinv);  c4.w = (float)(Dv*sinv);
    }
    *(float4*)(F + OFF_CF + (size_t)(t*DIM + pd)*4) = c4;
  }
}

template <int CTRL>
__device__ __forceinline__ float dpp_add(float x) {
  int yi = __builtin_amdgcn_update_dpp(0, __float_as_int(x), CTRL, 0xF, 0xF, true);
  return x + __int_as_float(yi);
}

// per-element: binary coarse over 7 regs, binary fine over LDS group, coeff read
#define SRCH(xx, CR, COLB, CF)                                                 \
  {                                                                            \
    bool c2 = (xx) >= CR[3];                                                   \
    float m5 = c2 ? CR[5] : CR[1];                                             \
    bool c1 = (xx) >= m5;                                                      \
    float m3 = c2 ? (c1 ? CR[6] : CR[4]) : (c1 ? CR[2] : CR[0]);               \
    bool c0 = (xx) >= m3;                                                      \
    int c = (((int)c2) << 2) | (((int)c1) << 1) | (int)c0;                     \
    float4 f0 = kv[(c << 6) + COLB];                                           \
    float4 f1 = kv[512 + (c << 6) + COLB];                                     \
    bool b2 = (xx) >= f0.w;                                                    \
    float n5 = b2 ? f1.y : f0.y;                                               \
    bool b1 = (xx) >= n5;                                                      \
    float n3 = b2 ? (b1 ? f1.z : f1.x) : (b1 ? f0.z : f0.x);                   \
    bool b0 = (xx) >= n3;                                                      \
    int p = (c << 3) | (((int)b2) << 2) | (((int)b1) << 1) | (int)b0;          \
    CF = kv[1024 + (p << 6) + COLB];                                           \
  }

#define MTH(xx, CF, OO, LL)                                                    \
  {                                                                            \
    float nu = fmaf(CF.x, (xx), CF.y);                                         \
    float de = fmaf(CF.z, (xx), CF.w);                                         \
    OO = __fdividef(nu, de);                                                   \
    LL = __log2f(fabsf(de));                                                   \
  }

// Main: 4 dims per lane. Wave owns 32 rows = 8 units of 4 rows; unit u:
// lane i handles row u*4+(i>>4), dims 4(i&15)..4(i&15)+3 (offset = 16i B ->
// dwordx4 loads/stores). 2-slot pipeline: math(unit k) while search(unit k+1),
// prefetch x(unit k+2); sched_barrier(0) fences. 16-lane DPP reduce per row.
__global__ __launch_bounds__(1024, 4) void nf_main(const float* __restrict__ X,
                                                   const float* __restrict__ F,
                                                   float* __restrict__ OUT,
                                                   float* __restrict__ LDo) {
  __shared__ float smem[20480];   // [0,4096) knots; [4096,20480) 64 coeff rows
  int t = threadIdx.x;
  {
    float4* dst = (float4*)smem;
    const float4* sk = (const float4*)F;
    dst[t] = sk[t];
    const float4* sc = (const float4*)(F + OFF_CF);
#pragma unroll
    for (int i = 0; i < 4; ++i) dst[1024 + t + i*1024] = sc[t + i*1024];
  }
  int lane = t & 63;
  int m = lane & 15;
  int rlane = lane >> 4;
  float cr0[7], cr1[7], cr2[7], cr3[7];
#pragma unroll
  for (int k = 0; k < 7; ++k) {
    cr0[k] = F[OFF_CRS + k*DIM + 4*m + 0];
    cr1[k] = F[OFF_CRS + k*DIM + 4*m + 1];
    cr2[k] = F[OFF_CRS + k*DIM + 4*m + 2];
    cr3[k] = F[OFF_CRS + k*DIM + 4*m + 3];
  }
  __syncthreads();
  const float4* kv = (const float4*)smem;
  int col0 = m, col1 = m + 16, col2 = m + 32, col3 = m + 48;

  int gw = blockIdx.x * 16 + (t >> 6);            // 0..8191; wave owns 32 rows
  const float4* Xq = (const float4*)(X + (size_t)gw*2048) + lane;
  float4*       Oq = (float4*)(OUT + (size_t)gw*2048) + lane;
  const float4* Pq = Xq + 128;                    // prefetch ptr (unit 2)
  float*        Lps = LDo + (size_t)gw*32 + rlane;

  // prologue: search unit 0; load x of unit 1
  float4 xA = Xq[0];
  float4 cfA0, cfA1, cfA2, cfA3;
  SRCH(xA.x, cr0, col0, cfA0)
  SRCH(xA.y, cr1, col1, cfA1)
  SRCH(xA.z, cr2, col2, cfA2)
  SRCH(xA.w, cr3, col3, cfA3)
  float4 xB = Xq[64];

#define STEP(KS, PQOFF, BUMP)                                                  \
  {                                                                            \
    float4 xF = Pq[PQOFF];                                                     \
    __builtin_amdgcn_sched_barrier(0);                                         \
    float o0,o1,o2,o3,l0,l1,l2,l3;                                             \
    MTH(xA.x, cfA0, o0, l0)                                                    \
    MTH(xA.y, cfA1, o1, l1)                                                    \
    MTH(xA.z, cfA2, o2, l2)                                                    \
    MTH(xA.w, cfA3, o3, l3)                                                    \
    float4 ov; ov.x=o0; ov.y=o1; ov.z=o2; ov.w=o3;                             \
    Oq[(KS & 3) * 64] = ov;                                                    \
    float s = (l0 + l1) + (l2 + l3);                                           \
    s = dpp_add<0x111>(s); s = dpp_add<0x112>(s);                              \
    s = dpp_add<0x114>(s); s = dpp_add<0x118>(s);                              \
    s *= -1.3862943611198906f;                                                 \
    if (m == 15) Lps[KS * 4] = s;                                              \
    __builtin_amdgcn_sched_barrier(0);                                         \
    SRCH(xB.x, cr0, col0, cfA0)                                                \
    SRCH(xB.y, cr1, col1, cfA1)                                                \
    SRCH(xB.z, cr2, col2, cfA2)                                                \
    SRCH(xB.w, cr3, col3, cfA3)                                                \
    xA = xB; xB = xF;                                                          \
    if (BUMP) Pq += 64;                                                        \
  }

  STEP(0, 0, 1)
  STEP(1, 0, 1)
  STEP(2, 0, 1)
  STEP(3, 0, 1)
  Oq += 256;
  STEP(4, 0, 1)
  STEP(5, 0, 0)      // prefetched unit 7; stop bumping
  STEP(6, 0, 0)      // re-reads unit 7 (value unused; avoids OOB)
  // epilogue: math(unit 7)
  {
    float o0,o1,o2,o3,l0,l1,l2,l3;
    MTH(xA.x, cfA0, o0, l0)
    MTH(xA.y, cfA1, o1, l1)
    MTH(xA.z, cfA2, o2, l2)
    MTH(xA.w, cfA3, o3, l3)
    float4 ov; ov.x=o0; ov.y=o1; ov.z=o2; ov.w=o3;
    Oq[3 * 64] = ov;
    float s = (l0 + l1) + (l2 + l3);
    s = dpp_add<0x111>(s); s = dpp_add<0x112>(s);
    s = dpp_add<0x114>(s); s = dpp_add<0x118>(s);
    s *= -1.3862943611198906f;
    if (m == 15) Lps[7 * 4] = s;
  }
#undef STEP
}

extern "C" void kernel_launch(void* const* d_in, const int* in_sizes, int n_in,
                              void* d_out, int out_size, void* d_ws, size_t ws_size,
                              hipStream_t stream) {
  const float* x  = (const float*)d_in[0];
  const float* uw = (const float*)d_in[1];
  const float* uh = (const float*)d_in[2];
  const float* ud = (const float*)d_in[3];
  const float* ul = (const float*)d_in[4];
  float* out = (float*)d_out;
  float* F = (float*)d_ws;
  nf_pre<<<DIM, 64, 0, stream>>>(uw, uh, ud, ul, F);
  nf_main<<<512, 1024, 0, stream>>>(x, F, out, out + (size_t)BATCH*DIM);
}

// Round 14
// 44.512 us; speedup vs baseline: 1.0456x; 1.0456x over previous
//
#include <hip/hip_runtime.h>

// NormalizingFlow: 4 layers of monotonic linear-rational splines (pyro-style),
// B=262144 rows, D=64 dims, K=8 bins.
//
// Each spline sub-piece (bin x lambda-half) is a Mobius map f(x)=(Ax+B)/(Cx+D);
// Mobius maps compose, so the 4-layer chain per dim is piecewise-Mobius with
// <= 61 pieces. Fused precompute (parallel phase 1) builds per-(d,piece)
// det-normalized (det=1) ABSOLUTE coefficient matrices; main kernel: 2-level
// LDS search + one LDS coeff gather + Mobius; lad = -2*ln|den| (det==1);
// single-instruction DPP wave reduce. 2-slot pipeline + sched_barrier fences;
// 3 groups x 5 units with group-local pointers (folded offsets).
// R14: R10 base + binary-select counts (provably equal to linear counts on
// the same sorted windows) — coarse B[8],B[16]..B[56]; fine B[8c+1..8c+7].

#define BATCH 262144
#define DIM   64
#define NLAY  4
#define NK    8

// float offsets in d_ws (units: floats from base)
#define OFF_KN0 0       // [8][64][4] fine knots bnd[8c+0..3] (slot0 = -3.0)
#define OFF_KN1 2048    // [8][64][4] fine knots bnd[8c+4..7]
#define OFF_CRS 4096    // [7][64] coarse knots bnd[8],bnd[16],...,bnd[56]
#define OFF_CF0 4544    // [61][64][4] piece coeffs (A,B,C,D) det-normalized

// Fused precompute: one block per dim d (64 blocks x 64 threads).
// Phase 1 parallelized over 32 threads: t = l*8 + k (layer l, bin k); each
// thread replicates the serial softmax-prefix rounding for its own bin.
__global__ void nf_pre(const float* __restrict__ uw, const float* __restrict__ uh,
                       const float* __restrict__ ud, const float* __restrict__ ul,
                       float* __restrict__ F) {
  __shared__ double Lb[NLAY][17], Ly[NLAY][17], LM[NLAY][16][4], Ld[NLAY][16];
  __shared__ double sx[64], Fb[65];
  int d = blockIdx.x;
  int t = threadIdx.x;

  if (t < 32) {
    int l = t >> 3, k = t & 7;
    const float* pw  = uw + (l*DIM + d)*NK;
    const float* ph  = uh + (l*DIM + d)*NK;
    const float* pdv = ud + (l*DIM + d)*(NK-1);
    const float* pl  = ul + (l*DIM + d)*NK;

    // widths softmax (serial-order rounding preserved)
    float ev[NK];
    float mw = pw[0];
    for (int j = 1; j < NK; ++j) mw = fmaxf(mw, pw[j]);
    float sw = 0.f;
    for (int j = 0; j < NK; ++j) { ev[j] = expf(pw[j] - mw); sw += ev[j]; }
    float invw = 1.f / sw;
    float cwe = 0.f, cwi = 0.f;
    for (int j = 0; j <= k; ++j) {
      float vj = 1e-3f + (1.f - 1e-3f * (float)NK) * (ev[j] * invw);
      cwe = cwi; cwi += vj;
    }
    float kwL = (k == 0) ? -3.f : 6.f * cwe - 3.f;
    float kwR = (k == 7) ?  3.f : 6.f * cwi - 3.f;
    float wwk = kwR - kwL;

    // heights softmax
    float mh = ph[0];
    for (int j = 1; j < NK; ++j) mh = fmaxf(mh, ph[j]);
    float sh = 0.f;
    for (int j = 0; j < NK; ++j) { ev[j] = expf(ph[j] - mh); sh += ev[j]; }
    float invh = 1.f / sh;
    float che = 0.f, chi = 0.f;
    for (int j = 0; j <= k; ++j) {
      float vj = 1e-3f + (1.f - 1e-3f * (float)NK) * (ev[j] * invh);
      che = chi; chi += vj;
    }
    float khL = (k == 0) ? -3.f : 6.f * che - 3.f;
    float khR = (k == 7) ?  3.f : 6.f * chi - 3.f;
    float hhk = khR - khL;

    // derivatives at both ends of bin k; lambda
    float dvk, dvk1;
    if (k == 0) dvk = 1.f;
    else { float u = pdv[k-1]; dvk  = 1e-3f + (fmaxf(u,0.f) + log1pf(expf(-fabsf(u)))); }
    if (k == 7) dvk1 = 1.f;
    else { float u = pdv[k];   dvk1 = 1e-3f + (fmaxf(u,0.f) + log1pf(expf(-fabsf(u)))); }
    float sg = 1.f / (1.f + expf(-pl[k]));
    float lmk = 0.95f * sg + 0.025f;

    float delta = hhk / wwk;
    float wbf = sqrtf(dvk / dvk1);
    float wcf = (lmk*dvk + (1.f-lmk)*wbf*dvk1) / delta;
    float yaf = khL, ybf = hhk + khL;
    float ycf = ((1.f-lmk)*yaf + lmk*wbf*ybf) / ((1.f-lmk) + lmk*wbf);

    if (k == 0) {
      Lb[l][0] = -3.0; Lb[l][16] = 3.0;
      Ly[l][0] = -3.0; Ly[l][16] = 3.0;
    }
    if (k) Lb[l][2*k] = (double)(kwL + 1.0e-6f);   // bin boundary (fp32 +EPS)
    Lb[l][2*k+1] = (double)kwL + (double)lmk*(double)wwk;  // theta==lambda
    Ly[l][2*k]   = (double)yaf;
    Ly[l][2*k+1] = (double)ycf;

    double icw = (double)kwL, iw = (double)wwk, il = (double)lmk;
    double wb = wbf, wc = wcf, ya = yaf, yb = ybf, yc = ycf;
    double n0 = ya*il, n1 = wc*yc - ya, d0 = il, d1 = wc - 1.0;
    double A = n1, Bv = n0*iw - n1*icw, C = d1, Dv = d0*iw - d1*icw;
    LM[l][2*k][0]=A; LM[l][2*k][1]=Bv; LM[l][2*k][2]=C; LM[l][2*k][3]=Dv;
    Ld[l][2*k] = log2(A*Dv - Bv*C);
    n0 = wc*yc - il*wb*yb; n1 = wb*yb - wc*yc; d0 = wc - il*wb; d1 = wb - wc;
    A = n1; Bv = n0*iw - n1*icw; C = d1; Dv = d0*iw - d1*icw;
    LM[l][2*k+1][0]=A; LM[l][2*k+1][1]=Bv; LM[l][2*k+1][2]=C; LM[l][2*k+1][3]=Dv;
    Ld[l][2*k+1] = log2(A*Dv - Bv*C);
  }
  __syncthreads();

  if (t < 60) {
    int lp  = t / 15;
    int mth = t % 15 + 1;
    double x = Lb[lp][mth];
    for (int q = lp - 1; q >= 0; --q) {
      int j = 0;
      for (int k = 1; k <= 15; ++k) j += (x >= Ly[q][k]) ? 1 : 0;
      const double* M = LM[q][j];
      x = (M[3]*x - M[1]) / (M[0] - M[2]*x);  // Mobius inverse
    }
    sx[t] = x;
  }
  __syncthreads();
  if (t < 60) {
    double x = sx[t];
    int r = 0;
    for (int s2 = 0; s2 < 60; ++s2) {
      double o = sx[s2];
      r += (o < x || (o == x && s2 < t)) ? 1 : 0;
    }
    Fb[r+1] = x;
  }
  if (t == 0)  Fb[0] = -3.0;
  if (t >= 60) Fb[t+1] = 3.0;   // Fb[61..64] geometry pads
  __syncthreads();

  // fp32 search tables
  {
    int j = t;
    float bf;
    if (j == 0)       bf = -3.0f;
    else if (j <= 60) bf = (float)Fb[j];
    else              bf = 1e30f;         // pads: never counted
    int cw = j >> 3, r8 = j & 7;
    if (r8 < 4) F[OFF_KN0 + (cw*DIM + d)*4 + r8]     = bf;
    else        F[OFF_KN1 + (cw*DIM + d)*4 + (r8-4)] = bf;
    if (j >= 8 && (j & 7) == 0 && j <= 56) F[OFF_CRS + (j/8 - 1)*DIM + d] = bf;
  }

  // per-piece composed ABSOLUTE coefficients (no recentering), det -> 1
  if (t < 61) {
    int p = t;
    double bl = Fb[p], br = Fb[p+1];
    float xmf = (float)(0.5*(bl+br));
    xmf = fminf(fmaxf(xmf, -3.f), 3.f);
    double y = (double)xmf;
    double A=1.0, Bv=0.0, C=0.0, Dv=1.0, ld2 = 0.0;
    for (int q = 0; q < NLAY; ++q) {
      int j = 0;
      for (int k = 1; k <= 15; ++k) j += (y >= Lb[q][k]) ? 1 : 0;
      const double* M = LM[q][j];
      ld2 += Ld[q][j];
      double A2 = M[0]*A + M[1]*C, B2 = M[0]*Bv + M[1]*Dv;
      double C2 = M[2]*A + M[3]*C, D2 = M[2]*Bv + M[3]*Dv;
      y = (M[0]*y + M[1]) / (M[2]*y + M[3]);
      A=A2; Bv=B2; C=C2; Dv=D2;
    }
    double sinv = exp2(-0.5 * ld2);              // det -> 1
    float4 c4;
    c4.x = (float)(A*sinv); c4.y = (float)(Bv*sinv);
    c4.z = (float)(C*sinv); c4.w = (float)(Dv*sinv);
    *(float4*)(F + OFF_CF0 + (size_t)(p*DIM + d)*4) = c4;
  }
}

template <int CTRL>
__device__ __forceinline__ float dpp_add(float x) {
  // bound_ctrl=true: invalid source lanes read 0 -> folds to one v_add_f32_dpp
  int yi = __builtin_amdgcn_update_dpp(0, __float_as_int(x), CTRL, 0xF, 0xF, true);
  return x + __int_as_float(yi);
}
// wave64 sum -> lane 63 (rocPRIM gfx9 sequence)
__device__ __forceinline__ float wave_sum63(float x) {
  x = dpp_add<0x111>(x);  // row_shr:1
  x = dpp_add<0x112>(x);  // row_shr:2
  x = dpp_add<0x114>(x);  // row_shr:4
  x = dpp_add<0x118>(x);  // row_shr:8
  x = dpp_add<0x142>(x);  // row_bcast:15
  x = dpp_add<0x143>(x);  // row_bcast:31
  return x;
}

// Binary-select count over the sorted coarse knots k1..k7 = B[8],B[16]..B[56].
// Provably equal to the linear count (xc>=k1)+...+(xc>=k7) on sorted data.
#define COARSEB(xx, C)                                                        \
  {                                                                           \
    bool c2b = (xx) >= k4;                                                    \
    float m5 = c2b ? k6 : k2;                                                 \
    bool c1b = (xx) >= m5;                                                    \
    float m3a = c1b ? k3 : k1;                                                \
    float m3b = c1b ? k7 : k5;                                                \
    float m3 = c2b ? m3b : m3a;                                               \
    bool c0b = (xx) >= m3;                                                    \
    C = (((int)c2b) << 2) | (((int)c1b) << 1) | (int)c0b;                     \
  }
// Binary-select count over the sorted fine window
// {f0.y,f0.z,f0.w,f1.x,f1.y,f1.z,f1.w} = B[8c+1..8c+7] (R10's exact window).
#define FINEPB(xx, cc, f0, f1, P)                                             \
  {                                                                           \
    bool b2 = (xx) >= f1.x;                                                   \
    float n5 = b2 ? f1.z : f0.z;                                              \
    bool b1 = (xx) >= n5;                                                     \
    float n3a = b1 ? f0.w : f0.y;                                             \
    float n3b = b1 ? f1.w : f1.y;                                             \
    float n3 = b2 ? n3b : n3a;                                                \
    bool b0 = (xx) >= n3;                                                     \
    P = ((cc) << 3) + (((int)b2) << 2) + (((int)b1) << 1) + (int)b0;          \
  }

// Main: lane = dim; wave owns 32 rows as 16 units of 2, software-pipelined:
//   R1: coarse(unit k+1) + issue fine-knot reads + X prefetch(unit k+2)
//   R2: math(unit k) with coeffs read LAST iteration (latency hidden)
//   R3: fine-count(unit k+1) + issue coeff reads
// 3 groups x (unroll 5) with group-local pointers: all global offsets <= 2304B
// fold into the load/store instructions.
__global__ __launch_bounds__(1024, 4) void nf_main(const float* __restrict__ X,
                                                   const float* __restrict__ F,
                                                   float* __restrict__ OUT,
                                                   float* __restrict__ LDo) {
  __shared__ float smem[19712];   // [0,4096): knots  [4096,19712): 61 coeff rows
  int t = threadIdx.x;
  {
    float4* dst = (float4*)smem;
    const float4* kt = (const float4*)(F + OFF_KN0);
    dst[t] = kt[t];
    const float4* ct = (const float4*)(F + OFF_CF0);
    for (int i = t; i < 3904; i += 1024) dst[1024 + i] = ct[i];
  }
  int d = t & 63;
  float k1 = F[OFF_CRS + 0*DIM + d];
  float k2 = F[OFF_CRS + 1*DIM + d];
  float k3 = F[OFF_CRS + 2*DIM + d];
  float k4 = F[OFF_CRS + 3*DIM + d];
  float k5 = F[OFF_CRS + 4*DIM + d];
  float k6 = F[OFF_CRS + 5*DIM + d];
  float k7 = F[OFF_CRS + 6*DIM + d];
  __syncthreads();
  const float4* skv = (const float4*)smem;

  int gw = blockIdx.x * 16 + (t >> 6);          // 0..8191; wave owns 32 rows
  const float* Xp = X   + (size_t)gw*32*DIM + d;
  float*       Op = OUT + (size_t)gw*32*DIM + d;
  float*       Lp = LDo + (size_t)gw*32;

  // ---- prologue: full search of unit 0; load x of unit 1 ----
  float xA0 = Xp[0], xA1 = Xp[64];
  float xB0 = Xp[128], xB1 = Xp[192];
  float xcA0 = __builtin_amdgcn_fmed3f(xA0, -3.f, 3.f);
  float xcA1 = __builtin_amdgcn_fmed3f(xA1, -3.f, 3.f);
  float4 cfA0, cfA1;
  {
    int c0, c1;
    COARSEB(xcA0, c0)
    COARSEB(xcA1, c1)
    float4 f00 = skv[(c0<<6)+d], f01 = skv[512+(c0<<6)+d];
    float4 f10 = skv[(c1<<6)+d], f11 = skv[512+(c1<<6)+d];
    int p0, p1;
    FINEPB(xcA0, c0, f00, f01, p0)
    FINEPB(xcA1, c1, f10, f11, p1)
    cfA0 = skv[1024+(p0<<6)+d];
    cfA1 = skv[1024+(p1<<6)+d];
  }

  for (int g = 0; g < 3; ++g) {
#pragma unroll
    for (int u = 0; u < 5; ++u) {
      // ---- R1: coarse(next unit), issue fine reads; prefetch x(unit+2) ----
      float xcB0 = __builtin_amdgcn_fmed3f(xB0, -3.f, 3.f);
      float xcB1 = __builtin_amdgcn_fmed3f(xB1, -3.f, 3.f);
      int cB0, cB1;
      COARSEB(xcB0, cB0)
      COARSEB(xcB1, cB1)
      float4 f00 = skv[(cB0<<6)+d], f01 = skv[512+(cB0<<6)+d];
      float4 f10 = skv[(cB1<<6)+d], f11 = skv[512+(cB1<<6)+d];
      int lo = (u == 4) ? ((g == 2) ? 5 : 6) : (u + 2);   // group-local prefetch unit
      float xF0 = Xp[lo*128], xF1 = Xp[lo*128 + 64];
      __builtin_amdgcn_sched_barrier(0);
      // ---- R2: math(unit g*5+u) using cfA (read last iteration) ----
      float num0 = fmaf(cfA0.x, xcA0, cfA0.y);
      float den0 = fmaf(cfA0.z, xcA0, cfA0.w);
      float o0 = (xA0 == xcA0) ? __fdividef(num0, den0) : xA0;
      float l0 = __log2f(fabsf(den0));
      float num1 = fmaf(cfA1.x, xcA1, cfA1.y);
      float den1 = fmaf(cfA1.z, xcA1, cfA1.w);
      float o1 = (xA1 == xcA1) ? __fdividef(num1, den1) : xA1;
      float l1 = __log2f(fabsf(den1));
      Op[u*128] = o0; Op[u*128 + 64] = o1;
      float s0 = wave_sum63(l0);
      float s1 = wave_sum63(l1);
      if (d == 63) {
        float2 v;
        v.x = s0 * -1.3862943611198906f;   // -2*ln2 folded once per row
        v.y = s1 * -1.3862943611198906f;
        *(float2*)(Lp + 2*u) = v;
      }
      __builtin_amdgcn_sched_barrier(0);
      // ---- R3: fine-count(next unit) + issue coeff reads ----
      int p0, p1;
      FINEPB(xcB0, cB0, f00, f01, p0)
      FINEPB(xcB1, cB1, f10, f11, p1)
      cfA0 = skv[1024+(p0<<6)+d];
      cfA1 = skv[1024+(p1<<6)+d];
      xA0 = xB0; xA1 = xB1; xcA0 = xcB0; xcA1 = xcB1;
      xB0 = xF0; xB1 = xF1;
    }
    Xp += 640; Op += 640; Lp += 10;
  }
  // ---- epilogue: math(unit 15); Op/Lp now point at its slots ----
  {
    float num0 = fmaf(cfA0.x, xcA0, cfA0.y);
    float den0 = fmaf(cfA0.z, xcA0, cfA0.w);
    float o0 = (xA0 == xcA0) ? __fdividef(num0, den0) : xA0;
    float l0 = __log2f(fabsf(den0));
    float num1 = fmaf(cfA1.x, xcA1, cfA1.y);
    float den1 = fmaf(cfA1.z, xcA1, cfA1.w);
    float o1 = (xA1 == xcA1) ? __fdividef(num1, den1) : xA1;
    float l1 = __log2f(fabsf(den1));
    Op[0] = o0; Op[64] = o1;
    float s0 = wave_sum63(l0);
    float s1 = wave_sum63(l1);
    if (d == 63) {
      float2 v;
      v.x = s0 * -1.3862943611198906f;
      v.y = s1 * -1.3862943611198906f;
      *(float2*)Lp = v;
    }
  }
}

extern "C" void kernel_launch(void* const* d_in, const int* in_sizes, int n_in,
                              void* d_out, int out_size, void* d_ws, size_t ws_size,
                              hipStream_t stream) {
  const float* x  = (const float*)d_in[0];
  const float* uw = (const float*)d_in[1];
  const float* uh = (const float*)d_in[2];
  const float* ud = (const float*)d_in[3];
  const float* ul = (const float*)d_in[4];
  float* out = (float*)d_out;
  float* F = (float*)d_ws;
  nf_pre<<<DIM, 64, 0, stream>>>(uw, uh, ud, ul, F);
  nf_main<<<512, 1024, 0, stream>>>(x, F, out, out + (size_t)BATCH*DIM);
}

// Round 15
// 42.741 us; speedup vs baseline: 1.0889x; 1.0414x over previous
//
#include <hip/hip_runtime.h>

// NormalizingFlow: 4 layers of monotonic linear-rational splines (pyro-style),
// B=262144 rows, D=64 dims, K=8 bins.
//
// Composed 4-layer chain per dim = piecewise-Mobius: 61 interior pieces +
// identity pieces (x<-3 row 0, x>=3 rows 62/63), det-normalized (det=1)
// ABSOLUTE fp32 coeffs, 64-row table. Main kernel (lane = dim, natural
// columns, conflict-free): linear counts on RAW x —
//   row = (x>=-3) + sum(x>=B[8m], m=1..7) + sum(x>=B[8c+1..8c+7])
// (same tables as the proven R10 kernel; B[61]=3.0) + one b128 coeff gather
// + Mobius; lad = -2 ln|den|; DPP reduce. No clamp / no outside-select.
// 2-slot pipeline + sched_barrier(0); 3 groups x 5 units, folded offsets.

#define BATCH 262144
#define DIM   64
#define NLAY  4
#define NK    8

// float offsets in d_ws (units: floats from base)
#define OFF_KN0 0       // [8][64][4] boundary slots B[8c+0..3]
#define OFF_KN1 2048    // [8][64][4] boundary slots B[8c+4..7]
#define OFF_CRS 4096    // [7][64] coarse knots B[8],B[16],...,B[56]
#define OFF_CF0 4544    // [64][64][4] piece coeffs (A,B,C,D); rows 0,62,63 id

// Fused precompute: one block per dim d (64 blocks x 64 threads).
// Phase 1 parallelized over 32 threads: t = l*8 + k (layer l, bin k).
__global__ void nf_pre(const float* __restrict__ uw, const float* __restrict__ uh,
                       const float* __restrict__ ud, const float* __restrict__ ul,
                       float* __restrict__ F) {
  __shared__ double Lb[NLAY][17], Ly[NLAY][17], LM[NLAY][16][4], Ld[NLAY][16];
  __shared__ double sx[64], Fb[65];
  int d = blockIdx.x;
  int t = threadIdx.x;

  if (t < 32) {
    int l = t >> 3, k = t & 7;
    const float* pw  = uw + (l*DIM + d)*NK;
    const float* ph  = uh + (l*DIM + d)*NK;
    const float* pdv = ud + (l*DIM + d)*(NK-1);
    const float* pl  = ul + (l*DIM + d)*NK;

    // widths softmax (serial-order rounding preserved)
    float ev[NK];
    float mw = pw[0];
    for (int j = 1; j < NK; ++j) mw = fmaxf(mw, pw[j]);
    float sw = 0.f;
    for (int j = 0; j < NK; ++j) { ev[j] = expf(pw[j] - mw); sw += ev[j]; }
    float invw = 1.f / sw;
    float cwe = 0.f, cwi = 0.f;
    for (int j = 0; j <= k; ++j) {
      float vj = 1e-3f + (1.f - 1e-3f * (float)NK) * (ev[j] * invw);
      cwe = cwi; cwi += vj;
    }
    float kwL = (k == 0) ? -3.f : 6.f * cwe - 3.f;
    float kwR = (k == 7) ?  3.f : 6.f * cwi - 3.f;
    float wwk = kwR - kwL;

    // heights softmax
    float mh = ph[0];
    for (int j = 1; j < NK; ++j) mh = fmaxf(mh, ph[j]);
    float sh = 0.f;
    for (int j = 0; j < NK; ++j) { ev[j] = expf(ph[j] - mh); sh += ev[j]; }
    float invh = 1.f / sh;
    float che = 0.f, chi = 0.f;
    for (int j = 0; j <= k; ++j) {
      float vj = 1e-3f + (1.f - 1e-3f * (float)NK) * (ev[j] * invh);
      che = chi; chi += vj;
    }
    float khL = (k == 0) ? -3.f : 6.f * che - 3.f;
    float khR = (k == 7) ?  3.f : 6.f * chi - 3.f;
    float hhk = khR - khL;

    // derivatives at both ends of bin k; lambda
    float dvk, dvk1;
    if (k == 0) dvk = 1.f;
    else { float u = pdv[k-1]; dvk  = 1e-3f + (fmaxf(u,0.f) + log1pf(expf(-fabsf(u)))); }
    if (k == 7) dvk1 = 1.f;
    else { float u = pdv[k];   dvk1 = 1e-3f + (fmaxf(u,0.f) + log1pf(expf(-fabsf(u)))); }
    float sg = 1.f / (1.f + expf(-pl[k]));
    float lmk = 0.95f * sg + 0.025f;

    float delta = hhk / wwk;
    float wbf = sqrtf(dvk / dvk1);
    float wcf = (lmk*dvk + (1.f-lmk)*wbf*dvk1) / delta;
    float yaf = khL, ybf = hhk + khL;
    float ycf = ((1.f-lmk)*yaf + lmk*wbf*ybf) / ((1.f-lmk) + lmk*wbf);

    if (k == 0) {
      Lb[l][0] = -3.0; Lb[l][16] = 3.0;
      Ly[l][0] = -3.0; Ly[l][16] = 3.0;
    }
    if (k) Lb[l][2*k] = (double)(kwL + 1.0e-6f);   // bin boundary (fp32 +EPS)
    Lb[l][2*k+1] = (double)kwL + (double)lmk*(double)wwk;  // theta==lambda
    Ly[l][2*k]   = (double)yaf;
    Ly[l][2*k+1] = (double)ycf;

    double icw = (double)kwL, iw = (double)wwk, il = (double)lmk;
    double wb = wbf, wc = wcf, ya = yaf, yb = ybf, yc = ycf;
    double n0 = ya*il, n1 = wc*yc - ya, d0 = il, d1 = wc - 1.0;
    double A = n1, Bv = n0*iw - n1*icw, C = d1, Dv = d0*iw - d1*icw;
    LM[l][2*k][0]=A; LM[l][2*k][1]=Bv; LM[l][2*k][2]=C; LM[l][2*k][3]=Dv;
    Ld[l][2*k] = log2(A*Dv - Bv*C);
    n0 = wc*yc - il*wb*yb; n1 = wb*yb - wc*yc; d0 = wc - il*wb; d1 = wb - wc;
    A = n1; Bv = n0*iw - n1*icw; C = d1; Dv = d0*iw - d1*icw;
    LM[l][2*k+1][0]=A; LM[l][2*k+1][1]=Bv; LM[l][2*k+1][2]=C; LM[l][2*k+1][3]=Dv;
    Ld[l][2*k+1] = log2(A*Dv - Bv*C);
  }
  __syncthreads();

  if (t < 60) {
    int lp  = t / 15;
    int mth = t % 15 + 1;
    double x = Lb[lp][mth];
    for (int q = lp - 1; q >= 0; --q) {
      int j = 0;
      for (int k = 1; k <= 15; ++k) j += (x >= Ly[q][k]) ? 1 : 0;
      const double* M = LM[q][j];
      x = (M[3]*x - M[1]) / (M[0] - M[2]*x);  // Mobius inverse
    }
    sx[t] = x;
  }
  __syncthreads();
  if (t < 60) {
    double x = sx[t];
    int r = 0;
    for (int s2 = 0; s2 < 60; ++s2) {
      double o = sx[s2];
      r += (o < x || (o == x && s2 < t)) ? 1 : 0;
    }
    Fb[r+1] = x;
  }
  if (t == 0)  Fb[0] = -3.0;
  if (t >= 60) Fb[t+1] = 3.0;   // Fb[61..64] geometry pads
  __syncthreads();

  // boundary slot table B[j]: B[0]=-3, B[1..60]=interior, B[61]=3, pads inf
  {
    int j = t;
    float bf;
    if (j == 0)       bf = -3.0f;
    else if (j <= 60) bf = (float)Fb[j];
    else if (j == 61) bf = 3.0f;
    else              bf = 1e30f;         // pads: never counted
    int cw = j >> 3, r8 = j & 7;
    if (r8 < 4) F[OFF_KN0 + (cw*DIM + d)*4 + r8]     = bf;
    else        F[OFF_KN1 + (cw*DIM + d)*4 + (r8-4)] = bf;
    if (j >= 8 && (j & 7) == 0 && j <= 56) F[OFF_CRS + (j/8 - 1)*DIM + d] = bf;
  }

  // coeff row t: rows 0, 62, 63 identity; rows 1..61 = interior piece t-1
  {
    float4 c4;
    if (t == 0 || t >= 62) {
      c4.x = 1.f; c4.y = 0.f; c4.z = 0.f; c4.w = 1.f;
    } else {
      int q = t - 1;
      double bl = Fb[q], br = Fb[q+1];
      float xmf = (float)(0.5*(bl+br));
      xmf = fminf(fmaxf(xmf, -3.f), 3.f);
      double y = (double)xmf;
      double A=1.0, Bv=0.0, C=0.0, Dv=1.0, ld2 = 0.0;
      for (int qq = 0; qq < NLAY; ++qq) {
        int j = 0;
        for (int k = 1; k <= 15; ++k) j += (y >= Lb[qq][k]) ? 1 : 0;
        const double* M = LM[qq][j];
        ld2 += Ld[qq][j];
        double A2 = M[0]*A + M[1]*C, B2 = M[0]*Bv + M[1]*Dv;
        double C2 = M[2]*A + M[3]*C, D2 = M[2]*Bv + M[3]*Dv;
        y = (M[0]*y + M[1]) / (M[2]*y + M[3]);
        A=A2; Bv=B2; C=C2; Dv=D2;
      }
      double sinv = exp2(-0.5 * ld2);              // det -> 1
      c4.x = (float)(A*sinv);  c4.y = (float)(Bv*sinv);
      c4.z = (float)(C*sinv);  c4.w = (float)(Dv*sinv);
    }
    *(float4*)(F + OFF_CF0 + (size_t)(t*DIM + d)*4) = c4;
  }
}

template <int CTRL>
__device__ __forceinline__ float dpp_add(float x) {
  // bound_ctrl=true: invalid source lanes read 0 -> folds to one v_add_f32_dpp
  int yi = __builtin_amdgcn_update_dpp(0, __float_as_int(x), CTRL, 0xF, 0xF, true);
  return x + __int_as_float(yi);
}
// wave64 sum -> lane 63 (rocPRIM gfx9 sequence)
__device__ __forceinline__ float wave_sum63(float x) {
  x = dpp_add<0x111>(x);  // row_shr:1
  x = dpp_add<0x112>(x);  // row_shr:2
  x = dpp_add<0x114>(x);  // row_shr:4
  x = dpp_add<0x118>(x);  // row_shr:8
  x = dpp_add<0x142>(x);  // row_bcast:15
  x = dpp_add<0x143>(x);  // row_bcast:31
  return x;
}

// linear counts on RAW x (R10-proven ILP-friendly form)
#define COARSE(xx) ((xx>=k1)+(xx>=k2)+(xx>=k3)+(xx>=k4)+(xx>=k5)+(xx>=k6)+(xx>=k7))
#define FINEI(xx, cc, f0, f1)                                                 \
  ((int)((xx) >= -3.f) + ((cc)<<3)                                            \
   + (int)((xx)>=f0.y)+(int)((xx)>=f0.z)+(int)((xx)>=f0.w)+(int)((xx)>=f1.x)  \
   + (int)((xx)>=f1.y)+(int)((xx)>=f1.z)+(int)((xx)>=f1.w))

// Main: lane = dim; wave owns 32 rows as 16 units of 2, software-pipelined:
//   R1: coarse(unit k+1) + issue fine-knot reads + X prefetch(unit k+2)
//   R2: math(unit k) with coeffs read LAST iteration (latency hidden)
//   R3: fine-count(unit k+1) + issue coeff reads
// 3 groups x (unroll 5) with group-local pointers: all global offsets <= 2304B
// fold into the load/store instructions.
__global__ __launch_bounds__(1024, 4) void nf_main(const float* __restrict__ X,
                                                   const float* __restrict__ F,
                                                   float* __restrict__ OUT,
                                                   float* __restrict__ LDo) {
  __shared__ float smem[20480];   // [0,4096): knots  [4096,20480): 64 coeff rows
  int t = threadIdx.x;
  {
    float4* dst = (float4*)smem;
    const float4* kt = (const float4*)(F + OFF_KN0);
    dst[t] = kt[t];
    const float4* ct = (const float4*)(F + OFF_CF0);
#pragma unroll
    for (int i = 0; i < 4; ++i) dst[1024 + t + i*1024] = ct[t + i*1024];
  }
  int d = t & 63;
  float k1 = F[OFF_CRS + 0*DIM + d];
  float k2 = F[OFF_CRS + 1*DIM + d];
  float k3 = F[OFF_CRS + 2*DIM + d];
  float k4 = F[OFF_CRS + 3*DIM + d];
  float k5 = F[OFF_CRS + 4*DIM + d];
  float k6 = F[OFF_CRS + 5*DIM + d];
  float k7 = F[OFF_CRS + 6*DIM + d];
  __syncthreads();
  const float4* skv = (const float4*)smem;

  int gw = blockIdx.x * 16 + (t >> 6);          // 0..8191; wave owns 32 rows
  const float* Xp = X   + (size_t)gw*32*DIM + d;
  float*       Op = OUT + (size_t)gw*32*DIM + d;
  float*       Lp = LDo + (size_t)gw*32;

  // ---- prologue: full search of unit 0; load x of unit 1 ----
  float xA0 = Xp[0], xA1 = Xp[64];
  float xB0 = Xp[128], xB1 = Xp[192];
  float4 cfA0, cfA1;
  {
    int c0 = COARSE(xA0), c1 = COARSE(xA1);
    float4 f00 = skv[(c0<<6)+d], f01 = skv[512+(c0<<6)+d];
    float4 f10 = skv[(c1<<6)+d], f11 = skv[512+(c1<<6)+d];
    int p0 = FINEI(xA0, c0, f00, f01);
    int p1 = FINEI(xA1, c1, f10, f11);
    cfA0 = skv[1024+(p0<<6)+d];
    cfA1 = skv[1024+(p1<<6)+d];
  }

  for (int g = 0; g < 3; ++g) {
#pragma unroll
    for (int u = 0; u < 5; ++u) {
      // ---- R1: coarse(next unit), issue fine reads; prefetch x(unit+2) ----
      int cB0 = COARSE(xB0), cB1 = COARSE(xB1);
      float4 f00 = skv[(cB0<<6)+d], f01 = skv[512+(cB0<<6)+d];
      float4 f10 = skv[(cB1<<6)+d], f11 = skv[512+(cB1<<6)+d];
      int lo = (u == 4) ? ((g == 2) ? 5 : 6) : (u + 2);   // group-local prefetch
      float xF0 = Xp[lo*128], xF1 = Xp[lo*128 + 64];
      __builtin_amdgcn_sched_barrier(0);
      // ---- R2: math(unit g*5+u) using cfA (read last iteration) ----
      float num0 = fmaf(cfA0.x, xA0, cfA0.y);
      float den0 = fmaf(cfA0.z, xA0, cfA0.w);
      float o0 = __fdividef(num0, den0);
      float l0 = __log2f(fabsf(den0));
      float num1 = fmaf(cfA1.x, xA1, cfA1.y);
      float den1 = fmaf(cfA1.z, xA1, cfA1.w);
      float o1 = __fdividef(num1, den1);
      float l1 = __log2f(fabsf(den1));
      Op[u*128] = o0; Op[u*128 + 64] = o1;
      float s0 = wave_sum63(l0);
      float s1 = wave_sum63(l1);
      if (d == 63) {
        float2 v;
        v.x = s0 * -1.3862943611198906f;   // -2*ln2 folded once per row
        v.y = s1 * -1.3862943611198906f;
        *(float2*)(Lp + 2*u) = v;
      }
      __builtin_amdgcn_sched_barrier(0);
      // ---- R3: fine-count(next unit) + issue coeff reads ----
      int p0 = FINEI(xB0, cB0, f00, f01);
      int p1 = FINEI(xB1, cB1, f10, f11);
      cfA0 = skv[1024+(p0<<6)+d];
      cfA1 = skv[1024+(p1<<6)+d];
      xA0 = xB0; xA1 = xB1;
      xB0 = xF0; xB1 = xF1;
    }
    Xp += 640; Op += 640; Lp += 10;
  }
  // ---- epilogue: math(unit 15); Op/Lp now point at its slots ----
  {
    float num0 = fmaf(cfA0.x, xA0, cfA0.y);
    float den0 = fmaf(cfA0.z, xA0, cfA0.w);
    float o0 = __fdividef(num0, den0);
    float l0 = __log2f(fabsf(den0));
    float num1 = fmaf(cfA1.x, xA1, cfA1.y);
    float den1 = fmaf(cfA1.z, xA1, cfA1.w);
    float o1 = __fdividef(num1, den1);
    float l1 = __log2f(fabsf(den1));
    Op[0] = o0; Op[64] = o1;
    float s0 = wave_sum63(l0);
    float s1 = wave_sum63(l1);
    if (d == 63) {
      float2 v;
      v.x = s0 * -1.3862943611198906f;
      v.y = s1 * -1.3862943611198906f;
      *(float2*)Lp = v;
    }
  }
}

extern "C" void kernel_launch(void* const* d_in, const int* in_sizes, int n_in,
                              void* d_out, int out_size, void* d_ws, size_t ws_size,
                              hipStream_t stream) {
  const float* x  = (const float*)d_in[0];
  const float* uw = (const float*)d_in[1];
  const float* uh = (const float*)d_in[2];
  const float* ud = (const float*)d_in[3];
  const float* ul = (const float*)d_in[4];
  float* out = (float*)d_out;
  float* F = (float*)d_ws;
  nf_pre<<<DIM, 64, 0, stream>>>(uw, uh, ud, ul, F);
  nf_main<<<512, 1024, 0, stream>>>(x, F, out, out + (size_t)BATCH*DIM);
}